// Round 2
// baseline (36733.005 us; speedup 1.0000x reference)
//
#include <hip/hip_runtime.h>
#include <stdint.h>

// ---------------- types ----------------
using bfrag_t = __attribute__((ext_vector_type(8))) short;  // 8 bf16 (4 VGPRs)
using f32x4   = __attribute__((ext_vector_type(4))) float;  // MFMA acc

#define HID  512
#define H3   256
#define RB   64       // batch rows per block (64 -> LDS 77KB -> 2 blocks/CU)
#define NTH  512      // 8 waves

__device__ __forceinline__ uint32_t bf16_rne(float f) {
    uint32_t u = __float_as_uint(f);
    return (u + 0x7fffu + ((u >> 16) & 1u)) >> 16;
}

__device__ __forceinline__ float fast_exp2(float x) {
#if __has_builtin(__builtin_amdgcn_exp2f)
    return __builtin_amdgcn_exp2f(x);
#else
    return exp2f(x);
#endif
}
__device__ __forceinline__ float fast_rcp(float x) {
#if __has_builtin(__builtin_amdgcn_rcpf)
    return __builtin_amdgcn_rcpf(x);
#else
    return 1.0f / x;
#endif
}
// tanh(x) = 1 - 2/(exp2(x*2*log2e)+1)
__device__ __forceinline__ float ftanh(float x) {
    float e = fast_exp2(x * 2.885390081777927f);
    return 1.0f - 2.0f * fast_rcp(e + 1.0f);
}

__device__ __forceinline__ bfrag_t frag_of(uint4 v) {
    union { uint4 u; bfrag_t f; } c; c.u = v; return c.f;
}

// ---------------- prep: swizzle W2^T / W3^T into MFMA A-fragment order (bf16) --------
// A-frag (16x16x32): lane l holds A[m = l&15][k = (l>>4)*8 + j], j=0..7 contiguous.
// Slot layout: [mt][kt][lane][8 bf16] -> one uint4 per (mt,kt,lane).
__global__ void prep_weights(const float* __restrict__ W2, const float* __restrict__ W3,
                             uint4* __restrict__ o2, uint4* __restrict__ o3)
{
    int id = blockIdx.x * 256 + threadIdx.x;
    if (id < 32768) {                       // W2: 32 mt * 16 kt * 64 lanes
        int l = id & 63, kt = (id >> 6) & 15, mt = id >> 10;
        int m = mt * 16 + (l & 15), k0 = kt * 32 + (l >> 4) * 8;
        uint32_t p[4];
        #pragma unroll
        for (int jj = 0; jj < 4; ++jj) {
            float v0 = W2[(k0 + jj * 2    ) * 512 + m];   // W2^T[m][k] = W2[k][m]
            float v1 = W2[(k0 + jj * 2 + 1) * 512 + m];
            p[jj] = bf16_rne(v0) | (bf16_rne(v1) << 16);
        }
        o2[id] = make_uint4(p[0], p[1], p[2], p[3]);
    } else if (id < 49152) {                // W3: 16 mt * 16 kt * 64 lanes
        int id2 = id - 32768;
        int l = id2 & 63, kt = (id2 >> 6) & 15, mt = id2 >> 10;
        int m = mt * 16 + (l & 15), k0 = kt * 32 + (l >> 4) * 8;
        uint32_t p[4];
        #pragma unroll
        for (int jj = 0; jj < 4; ++jj) {
            float v0 = W3[(k0 + jj * 2    ) * 256 + m];
            float v1 = W3[(k0 + jj * 2 + 1) * 256 + m];
            p[jj] = bf16_rne(v0) | (bf16_rne(v1) << 16);
        }
        o3[id2] = make_uint4(p[0], p[1], p[2], p[3]);
    }
}

// ---------------- main persistent kernel ----------------
// h stored transposed in LDS as chunks: hbuf[ck*RB + r] = 8 bf16 features
// [ck*8 .. ck*8+7] of batch row r. Simultaneously B-fragment source and
// epilogue target (C gives 4 contiguous features per lane -> ds_write_b64).
struct SmemT {
    uint4  hbuf[64 * RB];   // 64 KB: h1/h2 (512 feats) or h3 (first 32 chunks)
    float  w1[2][HID];
    float  b1[HID];
    float  b2[HID];
    float  b3[H3];
    float  w4[H3][2];
    float  b4[2];
    float  y [RB][2];
    float  z [RB][2];
    float  ya[RB][2];
    float  kv[RB][2];
};

__global__ __launch_bounds__(NTH, 4) void node_kernel(
    const float* __restrict__ y0, const float* __restrict__ tp,
    const float* __restrict__ W1, const float* __restrict__ b1g,
    const float* __restrict__ b2g, const float* __restrict__ b3g,
    const float* __restrict__ W4, const float* __restrict__ b4g,
    const uint4* __restrict__ w2A, const uint4* __restrict__ w3A,
    float* __restrict__ out, int Bn, int T)
{
    __shared__ SmemT s;
    const int tid = threadIdx.x;
    const int l   = tid & 63;
    const int w   = tid >> 6;          // wave 0..7
    const int b0  = blockIdx.x * RB;

    // stage small weights/biases to LDS (fp32)
    for (int i = tid; i < 2 * HID; i += NTH) s.w1[i >> 9][i & 511] = W1[i];
    for (int i = tid; i < HID; i += NTH) { s.b1[i] = b1g[i]; s.b2[i] = b2g[i]; }
    for (int i = tid; i < H3;  i += NTH) {
        s.b3[i] = b3g[i]; s.w4[i][0] = W4[i * 2]; s.w4[i][1] = W4[i * 2 + 1];
    }
    if (tid < 2) s.b4[tid] = b4g[tid];
    if (tid < RB) {
        float2 v = ((const float2*)y0)[b0 + tid];
        s.y[tid][0] = v.x; s.y[tid][1] = v.y;
        ((float2*)out)[b0 + tid] = v;          // trajectory[0] = y0
    }
    __syncthreads();

    for (int st = 0; st < T - 1; ++st) {
        float dt = tp[st + 1] - tp[st];
        if (tid < RB) {
            s.z [tid][0] = s.y[tid][0]; s.z [tid][1] = s.y[tid][1];
            s.ya[tid][0] = s.y[tid][0]; s.ya[tid][1] = s.y[tid][1];
        }
        __syncthreads();

        for (int e = 0; e < 4; ++e) {
            // ---- layer1: h1 = tanh(z @ W1 + b1)  (VALU, write bf16 chunks) ----
            #pragma unroll 4
            for (int i = 0; i < 8; ++i) {
                int idx = i * NTH + tid;            // 0..4095
                int ck = idx >> 6, r = idx & 63;    // ck wave-uniform
                float z0 = s.z[r][0], z1 = s.z[r][1];
                uint32_t p[4];
                #pragma unroll
                for (int jj = 0; jj < 4; ++jj) {
                    int f = ck * 8 + jj * 2;
                    float h0 = ftanh(z0 * s.w1[0][f]     + z1 * s.w1[1][f]     + s.b1[f]);
                    float h1 = ftanh(z0 * s.w1[0][f + 1] + z1 * s.w1[1][f + 1] + s.b1[f + 1]);
                    p[jj] = bf16_rne(h0) | (bf16_rne(h1) << 16);
                }
                s.hbuf[ck * RB + r] = make_uint4(p[0], p[1], p[2], p[3]);
            }
            __syncthreads();

            // ---- layer2: h2^T = W2^T @ h1^T  (M=512 feat, N=64 rows, K=512) ----
            {
                const int q = l >> 4, rr = l & 15;
                f32x4 acc[4][4];
                #pragma unroll
                for (int mt = 0; mt < 4; ++mt)
                    #pragma unroll
                    for (int nt = 0; nt < 4; ++nt) acc[mt][nt] = (f32x4){0.f, 0.f, 0.f, 0.f};
                uint4 aC[4], aN[4];
                #pragma unroll
                for (int mt = 0; mt < 4; ++mt) aC[mt] = w2A[((w * 4 + mt) * 16) * 64 + l];
                for (int kt = 0; kt < 16; ++kt) {
                    uint4 bF[4];
                    #pragma unroll
                    for (int nt = 0; nt < 4; ++nt)
                        bF[nt] = s.hbuf[(kt * 4 + q) * RB + nt * 16 + rr];
                    if (kt < 15) {
                        #pragma unroll
                        for (int mt = 0; mt < 4; ++mt)
                            aN[mt] = w2A[(((w * 4 + mt) * 16) + kt + 1) * 64 + l];
                    }
                    #pragma unroll
                    for (int mt = 0; mt < 4; ++mt)
                        #pragma unroll
                        for (int nt = 0; nt < 4; ++nt)
                            acc[mt][nt] = __builtin_amdgcn_mfma_f32_16x16x32_bf16(
                                frag_of(aC[mt]), frag_of(bF[nt]), acc[mt][nt], 0, 0, 0);
                    #pragma unroll
                    for (int mt = 0; mt < 4; ++mt) aC[mt] = aN[mt];
                }
                __syncthreads();   // all waves done reading h1
                // epilogue: +bias, tanh, bf16, overwrite hbuf with h2
                #pragma unroll
                for (int mt = 0; mt < 4; ++mt) {
                    int mb = (w * 4 + mt) * 16 + q * 4;   // 4 contiguous features
                    float c0 = s.b2[mb], c1 = s.b2[mb + 1], c2 = s.b2[mb + 2], c3 = s.b2[mb + 3];
                    #pragma unroll
                    for (int nt = 0; nt < 4; ++nt) {
                        int n = nt * 16 + rr;
                        f32x4 c = acc[mt][nt];
                        uint32_t lo = bf16_rne(ftanh(c[0] + c0)) | (bf16_rne(ftanh(c[1] + c1)) << 16);
                        uint32_t hi = bf16_rne(ftanh(c[2] + c2)) | (bf16_rne(ftanh(c[3] + c3)) << 16);
                        ((uint2*)s.hbuf)[(((mb >> 3) * RB + n) << 1) | ((mb & 7) >> 2)] =
                            make_uint2(lo, hi);
                    }
                }
                __syncthreads();
            }

            // ---- layer3: h3^T = W3^T @ h2^T  (M=256, N=64, K=512) ----
            {
                const int q = l >> 4, rr = l & 15;
                f32x4 acc[2][4];
                #pragma unroll
                for (int mt = 0; mt < 2; ++mt)
                    #pragma unroll
                    for (int nt = 0; nt < 4; ++nt) acc[mt][nt] = (f32x4){0.f, 0.f, 0.f, 0.f};
                uint4 aC[2], aN[2];
                #pragma unroll
                for (int mt = 0; mt < 2; ++mt) aC[mt] = w3A[((w * 2 + mt) * 16) * 64 + l];
                for (int kt = 0; kt < 16; ++kt) {
                    uint4 bF[4];
                    #pragma unroll
                    for (int nt = 0; nt < 4; ++nt)
                        bF[nt] = s.hbuf[(kt * 4 + q) * RB + nt * 16 + rr];
                    if (kt < 15) {
                        #pragma unroll
                        for (int mt = 0; mt < 2; ++mt)
                            aN[mt] = w3A[(((w * 2 + mt) * 16) + kt + 1) * 64 + l];
                    }
                    #pragma unroll
                    for (int mt = 0; mt < 2; ++mt)
                        #pragma unroll
                        for (int nt = 0; nt < 4; ++nt)
                            acc[mt][nt] = __builtin_amdgcn_mfma_f32_16x16x32_bf16(
                                frag_of(aC[mt]), frag_of(bF[nt]), acc[mt][nt], 0, 0, 0);
                    #pragma unroll
                    for (int mt = 0; mt < 2; ++mt) aC[mt] = aN[mt];
                }
                __syncthreads();   // all waves done reading h2
                #pragma unroll
                for (int mt = 0; mt < 2; ++mt) {
                    int mb = (w * 2 + mt) * 16 + q * 4;  // feature 0..255 -> ck 0..31
                    float c0 = s.b3[mb], c1 = s.b3[mb + 1], c2 = s.b3[mb + 2], c3 = s.b3[mb + 3];
                    #pragma unroll
                    for (int nt = 0; nt < 4; ++nt) {
                        int n = nt * 16 + rr;
                        f32x4 c = acc[mt][nt];
                        uint32_t lo = bf16_rne(ftanh(c[0] + c0)) | (bf16_rne(ftanh(c[1] + c1)) << 16);
                        uint32_t hi = bf16_rne(ftanh(c[2] + c2)) | (bf16_rne(ftanh(c[3] + c3)) << 16);
                        ((uint2*)s.hbuf)[(((mb >> 3) * RB + n) << 1) | ((mb & 7) >> 2)] =
                            make_uint2(lo, hi);
                    }
                }
                __syncthreads();
            }

            // ---- layer4: k = h3 @ W4 + b4  (fp32 VALU + 8-lane shuffle reduce) ----
            {
                int r = tid >> 3, qq = tid & 7;
                float a0 = 0.f, a1 = 0.f;
                #pragma unroll
                for (int j = 0; j < 4; ++j) {
                    int ck = qq * 4 + j;
                    uint4 hv = s.hbuf[ck * RB + r];
                    const uint32_t* pu = (const uint32_t*)&hv;
                    #pragma unroll
                    for (int jj = 0; jj < 4; ++jj) {
                        uint32_t uu = pu[jj];
                        float h0 = __uint_as_float(uu << 16);
                        float h1 = __uint_as_float(uu & 0xffff0000u);
                        int f = ck * 8 + jj * 2;
                        a0 += h0 * s.w4[f][0] + h1 * s.w4[f + 1][0];
                        a1 += h0 * s.w4[f][1] + h1 * s.w4[f + 1][1];
                    }
                }
                a0 += __shfl_xor(a0, 1, 8); a0 += __shfl_xor(a0, 2, 8); a0 += __shfl_xor(a0, 4, 8);
                a1 += __shfl_xor(a1, 1, 8); a1 += __shfl_xor(a1, 2, 8); a1 += __shfl_xor(a1, 4, 8);
                if (qq == 0) { s.kv[r][0] = a0 + s.b4[0]; s.kv[r][1] = a1 + s.b4[1]; }
            }
            __syncthreads();

            // ---- RK4 combine ----
            if (tid < RB) {
                float k0 = s.kv[tid][0], k1 = s.kv[tid][1];
                float wg = (e == 0 || e == 3) ? dt * (1.f / 6.f) : dt * (1.f / 3.f);
                s.ya[tid][0] += wg * k0; s.ya[tid][1] += wg * k1;
                if (e < 3) {
                    float aa = (e == 2) ? dt : dt * 0.5f;
                    s.z[tid][0] = s.y[tid][0] + aa * k0;
                    s.z[tid][1] = s.y[tid][1] + aa * k1;
                } else {
                    s.y[tid][0] = s.ya[tid][0]; s.y[tid][1] = s.ya[tid][1];
                    ((float2*)out)[(size_t)(st + 1) * Bn + b0 + tid] =
                        make_float2(s.ya[tid][0], s.ya[tid][1]);
                }
            }
            __syncthreads();
        }
    }
}

extern "C" void kernel_launch(void* const* d_in, const int* in_sizes, int n_in,
                              void* d_out, int out_size, void* d_ws, size_t ws_size,
                              hipStream_t stream)
{
    const float* y0 = (const float*)d_in[0];
    const float* tp = (const float*)d_in[1];
    const float* W1 = (const float*)d_in[2];
    const float* b1 = (const float*)d_in[3];
    const float* W2 = (const float*)d_in[4];
    const float* b2 = (const float*)d_in[5];
    const float* W3 = (const float*)d_in[6];
    const float* b3 = (const float*)d_in[7];
    const float* W4 = (const float*)d_in[8];
    const float* b4 = (const float*)d_in[9];
    float* out = (float*)d_out;

    const int Bn = in_sizes[0] / 2;
    const int T  = in_sizes[1];

    uint4* w2A = (uint4*)d_ws;          // 32768 uint4 = 512 KB
    uint4* w3A = w2A + 32768;           // 16384 uint4 = 256 KB

    prep_weights<<<192, 256, 0, stream>>>(W2, W3, w2A, w3A);
    node_kernel<<<Bn / RB, NTH, 0, stream>>>(y0, tp, W1, b1, b2, b3, W4, b4,
                                             w2A, w3A, out, Bn, T);
}

// Round 3
// 26277.255 us; speedup vs baseline: 1.3979x; 1.3979x over previous
//
#include <hip/hip_runtime.h>
#include <hip/hip_bf16.h>
#include <stdint.h>

// ---------------- types ----------------
using bfrag_t = __attribute__((ext_vector_type(8))) short;  // 8 bf16 (4 VGPRs)
using f32x4   = __attribute__((ext_vector_type(4))) float;  // MFMA acc

#define HID  512
#define H3   256
#define RB   128      // batch rows per block (R2 showed RB=64 doubles weight-stream -> L2 miss blowup)
#define NTH  512      // 8 waves
#define KSC  2.885390081777927f   // 2*log2(e): tanh(x) = 1 - 2/(exp2(KSC*x)+1)

static __device__ __forceinline__ uint32_t bf16_rne(float f) {
    uint32_t u = __float_as_uint(f);
    return (u + 0x7fffu + ((u >> 16) & 1u)) >> 16;
}
static __device__ __forceinline__ uint32_t pk_bf16(float a, float b) {
    union { __hip_bfloat162 h; uint32_t u; } c;
    c.h = __float22bfloat162_rn(make_float2(a, b));   // v_cvt_pk_bf16_f32 on gfx950
    return c.u;
}
static __device__ __forceinline__ float fast_exp2(float x) {
#if __has_builtin(__builtin_amdgcn_exp2f)
    return __builtin_amdgcn_exp2f(x);
#else
    return exp2f(x);
#endif
}
static __device__ __forceinline__ float fast_rcp(float x) {
#if __has_builtin(__builtin_amdgcn_rcpf)
    return __builtin_amdgcn_rcpf(x);
#else
    return 1.0f / x;
#endif
}
// input is PRE-SCALED by KSC (weights/biases scaled in prep)
static __device__ __forceinline__ float ftanh_s(float xs) {
    float e = fast_exp2(xs);
    return 1.0f - 2.0f * fast_rcp(e + 1.0f);
}
static __device__ __forceinline__ bfrag_t frag_of(uint4 v) {
    union { uint4 u; bfrag_t f; } c; c.u = v; return c.f;
}

// ---------------- prep: swizzle W2^T / W3^T (scaled by KSC) into MFMA A-frag order;
// also emit scaled W1-pack [ck][w0*8|w1*8|b*8] and scaled b2/b3. ----------------
__global__ void prep_weights(const float* __restrict__ W1, const float* __restrict__ b1,
                             const float* __restrict__ W2, const float* __restrict__ b2,
                             const float* __restrict__ W3, const float* __restrict__ b3,
                             uint4* __restrict__ o2, uint4* __restrict__ o3,
                             float* __restrict__ w1p, float* __restrict__ b2s,
                             float* __restrict__ b3s)
{
    int id = blockIdx.x * 256 + threadIdx.x;
    if (id < 32768) {                       // W2: 32 mt * 16 kt * 64 lanes
        int l = id & 63, kt = (id >> 6) & 15, mt = id >> 10;
        int m = mt * 16 + (l & 15), k0 = kt * 32 + (l >> 4) * 8;
        uint32_t p[4];
        #pragma unroll
        for (int jj = 0; jj < 4; ++jj) {
            float v0 = KSC * W2[(k0 + jj * 2    ) * 512 + m];  // W2^T[m][k] = W2[k][m]
            float v1 = KSC * W2[(k0 + jj * 2 + 1) * 512 + m];
            p[jj] = bf16_rne(v0) | (bf16_rne(v1) << 16);
        }
        o2[id] = make_uint4(p[0], p[1], p[2], p[3]);
    } else if (id < 49152) {                // W3: 16 mt * 16 kt * 64 lanes
        int id2 = id - 32768;
        int l = id2 & 63, kt = (id2 >> 6) & 15, mt = id2 >> 10;
        int m = mt * 16 + (l & 15), k0 = kt * 32 + (l >> 4) * 8;
        uint32_t p[4];
        #pragma unroll
        for (int jj = 0; jj < 4; ++jj) {
            float v0 = KSC * W3[(k0 + jj * 2    ) * 256 + m];
            float v1 = KSC * W3[(k0 + jj * 2 + 1) * 256 + m];
            p[jj] = bf16_rne(v0) | (bf16_rne(v1) << 16);
        }
        o3[id2] = make_uint4(p[0], p[1], p[2], p[3]);
    } else if (id < 49152 + 1536) {         // W1 pack: 64 chunks x 24 floats
        int t = id - 49152;
        int ck = t / 24, j = t % 24;
        int f = ck * 8 + (j & 7);
        float v = (j < 8) ? W1[f] : (j < 16) ? W1[512 + f] : b1[f];
        w1p[t] = KSC * v;
    } else if (id < 49152 + 1536 + 512) {
        int i = id - 49152 - 1536; b2s[i] = KSC * b2[i];
    } else if (id < 49152 + 1536 + 512 + 256) {
        int i = id - 49152 - 1536 - 512; b3s[i] = KSC * b3[i];
    }
}

// ---------------- main persistent kernel ----------------
struct SmemT {
    uint4  hbuf[64 * RB];   // 128 KB: h1/h2 (512 feats) or h3 (first 32 chunks)
    float  b2[HID];          // scaled
    float  b3[H3];           // scaled
    float  y [RB][2];
    float  z [RB][2];
    float  ya[RB][2];
    float  part[4][RB][2];   // layer4 partials
};

__global__ __launch_bounds__(NTH, 2) void node_kernel(
    const float* __restrict__ y0, const float* __restrict__ tp,
    const float* __restrict__ W4g, const float* __restrict__ b4g,
    const uint4* __restrict__ w2A, const uint4* __restrict__ w3A,
    const float* __restrict__ w1p, const float* __restrict__ b2s,
    const float* __restrict__ b3s,
    float* __restrict__ out, int Bn, int T)
{
    __shared__ SmemT s;
    const int tid = threadIdx.x;
    const int l   = tid & 63;
    const int w   = tid >> 6;                                  // wave 0..7
    const int wu  = __builtin_amdgcn_readfirstlane(w);         // provably uniform
    const int b0  = blockIdx.x * RB;

    // stage biases (scaled) to LDS; init y / out
    for (int i = tid; i < HID; i += NTH) s.b2[i] = b2s[i];
    for (int i = tid; i < H3;  i += NTH) s.b3[i] = b3s[i];
    if (tid < RB) {
        float2 v = ((const float2*)y0)[b0 + tid];
        s.y[tid][0] = v.x; s.y[tid][1] = v.y;
        ((float2*)out)[b0 + tid] = v;          // trajectory[0] = y0
    }
    __syncthreads();

    const float* w1w = w1p + wu * 8 * 24;      // this wave's 8 chunks (uniform)

    for (int st = 0; st < T - 1; ++st) {
        float dt = tp[st + 1] - tp[st];
        if (tid < RB) {
            s.z [tid][0] = s.y[tid][0]; s.z [tid][1] = s.y[tid][1];
            s.ya[tid][0] = s.y[tid][0]; s.ya[tid][1] = s.y[tid][1];
        }
        __syncthreads();

        for (int e = 0; e < 4; ++e) {
            // ---- layer1: h1 = tanh(z @ W1 + b1); weights via uniform s_loads ----
            {
                float zl0 = s.z[l][0],      zl1 = s.z[l][1];
                float zh0 = s.z[64 + l][0], zh1 = s.z[64 + l][1];
                #pragma unroll
                for (int i = 0; i < 8; ++i) {
                    const float* P = w1w + i * 24;   // uniform -> s_load
                    int ck = wu * 8 + i;
                    float xa[8], xb[8];
                    #pragma unroll
                    for (int jj = 0; jj < 8; ++jj) {
                        float wa = P[jj], wb = P[8 + jj], bb = P[16 + jj];
                        xa[jj] = ftanh_s(fmaf(zl0, wa, fmaf(zl1, wb, bb)));
                        xb[jj] = ftanh_s(fmaf(zh0, wa, fmaf(zh1, wb, bb)));
                    }
                    s.hbuf[ck * RB + l] = make_uint4(
                        pk_bf16(xa[0], xa[1]), pk_bf16(xa[2], xa[3]),
                        pk_bf16(xa[4], xa[5]), pk_bf16(xa[6], xa[7]));
                    s.hbuf[ck * RB + 64 + l] = make_uint4(
                        pk_bf16(xb[0], xb[1]), pk_bf16(xb[2], xb[3]),
                        pk_bf16(xb[4], xb[5]), pk_bf16(xb[6], xb[7]));
                }
            }
            __syncthreads();

            // ---- layer2: h2^T = W2^T @ h1^T + b2 (in acc)  M=512, N=128, K=512 ----
            {
                const int q = l >> 4, rr = l & 15;
                f32x4 acc[4][8];
                #pragma unroll
                for (int mt = 0; mt < 4; ++mt) {
                    int mb = (w * 4 + mt) * 16 + q * 4;
                    float4 bi = *(const float4*)&s.b2[mb];    // broadcast within rr-group
                    #pragma unroll
                    for (int nt = 0; nt < 8; ++nt) acc[mt][nt] = (f32x4){bi.x, bi.y, bi.z, bi.w};
                }
                uint4 aC[4], aN[4];
                #pragma unroll
                for (int mt = 0; mt < 4; ++mt) aC[mt] = w2A[((w * 4 + mt) * 16) * 64 + l];
                for (int kt = 0; kt < 16; ++kt) {
                    uint4 bF[8];
                    #pragma unroll
                    for (int nt = 0; nt < 8; ++nt)
                        bF[nt] = s.hbuf[(kt * 4 + q) * RB + nt * 16 + rr];
                    if (kt < 15) {
                        #pragma unroll
                        for (int mt = 0; mt < 4; ++mt)
                            aN[mt] = w2A[(((w * 4 + mt) * 16) + kt + 1) * 64 + l];
                    }
                    #pragma unroll
                    for (int mt = 0; mt < 4; ++mt)
                        #pragma unroll
                        for (int nt = 0; nt < 8; ++nt)
                            acc[mt][nt] = __builtin_amdgcn_mfma_f32_16x16x32_bf16(
                                frag_of(aC[mt]), frag_of(bF[nt]), acc[mt][nt], 0, 0, 0);
                    #pragma unroll
                    for (int mt = 0; mt < 4; ++mt) aC[mt] = aN[mt];
                }
                __syncthreads();   // all waves done reading h1
                // epilogue: tanh (pre-scaled), pack, overwrite hbuf with h2
                #pragma unroll
                for (int mt = 0; mt < 4; ++mt) {
                    int mb = (w * 4 + mt) * 16 + q * 4;
                    int ck = mb >> 3, hi = (mb >> 2) & 1;
                    #pragma unroll
                    for (int nt = 0; nt < 8; ++nt) {
                        int n = nt * 16 + rr;
                        f32x4 c = acc[mt][nt];
                        uint32_t u0 = pk_bf16(ftanh_s(c[0]), ftanh_s(c[1]));
                        uint32_t u1 = pk_bf16(ftanh_s(c[2]), ftanh_s(c[3]));
                        ((uint2*)s.hbuf)[((ck * RB + n) << 1) | hi] = make_uint2(u0, u1);
                    }
                }
                __syncthreads();
            }

            // ---- layer3: h3^T = W3^T @ h2^T + b3  M=256, N=128, K=512 ----
            {
                const int q = l >> 4, rr = l & 15;
                const int mg = w >> 1, ng = w & 1;   // 4 m-groups x 2 n-groups
                f32x4 acc[4][4];
                #pragma unroll
                for (int mt = 0; mt < 4; ++mt) {
                    int mb = (mg * 4 + mt) * 16 + q * 4;
                    float4 bi = *(const float4*)&s.b3[mb];
                    #pragma unroll
                    for (int nt = 0; nt < 4; ++nt) acc[mt][nt] = (f32x4){bi.x, bi.y, bi.z, bi.w};
                }
                uint4 aC[4], aN[4];
                #pragma unroll
                for (int mt = 0; mt < 4; ++mt) aC[mt] = w3A[((mg * 4 + mt) * 16) * 64 + l];
                for (int kt = 0; kt < 16; ++kt) {
                    uint4 bF[4];
                    #pragma unroll
                    for (int nt = 0; nt < 4; ++nt)
                        bF[nt] = s.hbuf[(kt * 4 + q) * RB + ng * 64 + nt * 16 + rr];
                    if (kt < 15) {
                        #pragma unroll
                        for (int mt = 0; mt < 4; ++mt)
                            aN[mt] = w3A[(((mg * 4 + mt) * 16) + kt + 1) * 64 + l];
                    }
                    #pragma unroll
                    for (int mt = 0; mt < 4; ++mt)
                        #pragma unroll
                        for (int nt = 0; nt < 4; ++nt)
                            acc[mt][nt] = __builtin_amdgcn_mfma_f32_16x16x32_bf16(
                                frag_of(aC[mt]), frag_of(bF[nt]), acc[mt][nt], 0, 0, 0);
                    #pragma unroll
                    for (int mt = 0; mt < 4; ++mt) aC[mt] = aN[mt];
                }
                __syncthreads();   // all waves done reading h2
                #pragma unroll
                for (int mt = 0; mt < 4; ++mt) {
                    int mb = (mg * 4 + mt) * 16 + q * 4;  // feature 0..255 -> ck 0..31
                    int ck = mb >> 3, hi = (mb >> 2) & 1;
                    #pragma unroll
                    for (int nt = 0; nt < 4; ++nt) {
                        int n = ng * 64 + nt * 16 + rr;
                        f32x4 c = acc[mt][nt];
                        uint32_t u0 = pk_bf16(ftanh_s(c[0]), ftanh_s(c[1]));
                        uint32_t u1 = pk_bf16(ftanh_s(c[2]), ftanh_s(c[3]));
                        ((uint2*)s.hbuf)[((ck * RB + n) << 1) | hi] = make_uint2(u0, u1);
                    }
                }
                __syncthreads();
            }

            // ---- layer4 partials: contiguous-row reads, uniform W4 s_loads ----
            {
                int r  = tid & 127;                      // = l + 64*(w&1): contiguous
                int qq = __builtin_amdgcn_readfirstlane(tid >> 7);  // 0..3 uniform
                float a0 = 0.f, a1 = 0.f;
                #pragma unroll
                for (int j = 0; j < 8; ++j) {
                    int ck = qq * 8 + j;
                    uint4 hv = s.hbuf[ck * RB + r];
                    const uint32_t* pu = (const uint32_t*)&hv;
                    #pragma unroll
                    for (int jj = 0; jj < 4; ++jj) {
                        uint32_t uu = pu[jj];
                        float h0 = __uint_as_float(uu << 16);
                        float h1 = __uint_as_float(uu & 0xffff0000u);
                        int f = ck * 8 + jj * 2;                     // uniform
                        a0 = fmaf(h0, W4g[f * 2],     fmaf(h1, W4g[f * 2 + 2], a0));
                        a1 = fmaf(h0, W4g[f * 2 + 1], fmaf(h1, W4g[f * 2 + 3], a1));
                    }
                }
                s.part[qq][r][0] = a0; s.part[qq][r][1] = a1;
            }
            __syncthreads();

            // ---- reduce partials + RK4 combine ----
            if (tid < RB) {
                float k0 = s.part[0][tid][0] + s.part[1][tid][0]
                         + s.part[2][tid][0] + s.part[3][tid][0] + b4g[0];
                float k1 = s.part[0][tid][1] + s.part[1][tid][1]
                         + s.part[2][tid][1] + s.part[3][tid][1] + b4g[1];
                float wg = (e == 0 || e == 3) ? dt * (1.f / 6.f) : dt * (1.f / 3.f);
                s.ya[tid][0] += wg * k0; s.ya[tid][1] += wg * k1;
                if (e < 3) {
                    float aa = (e == 2) ? dt : dt * 0.5f;
                    s.z[tid][0] = s.y[tid][0] + aa * k0;
                    s.z[tid][1] = s.y[tid][1] + aa * k1;
                } else {
                    s.y[tid][0] = s.ya[tid][0]; s.y[tid][1] = s.ya[tid][1];
                    ((float2*)out)[(size_t)(st + 1) * Bn + b0 + tid] =
                        make_float2(s.ya[tid][0], s.ya[tid][1]);
                }
            }
            __syncthreads();
        }
    }
}

extern "C" void kernel_launch(void* const* d_in, const int* in_sizes, int n_in,
                              void* d_out, int out_size, void* d_ws, size_t ws_size,
                              hipStream_t stream)
{
    const float* y0 = (const float*)d_in[0];
    const float* tp = (const float*)d_in[1];
    const float* W1 = (const float*)d_in[2];
    const float* b1 = (const float*)d_in[3];
    const float* W2 = (const float*)d_in[4];
    const float* b2 = (const float*)d_in[5];
    const float* W3 = (const float*)d_in[6];
    const float* b3 = (const float*)d_in[7];
    const float* W4 = (const float*)d_in[8];
    const float* b4 = (const float*)d_in[9];
    float* out = (float*)d_out;

    const int Bn = in_sizes[0] / 2;
    const int T  = in_sizes[1];

    uint4* w2A = (uint4*)d_ws;            // 32768 uint4 = 512 KB
    uint4* w3A = w2A + 32768;             // 16384 uint4 = 256 KB
    float* w1p = (float*)(w3A + 16384);   // 1536 floats (scaled W1 pack)
    float* b2s = w1p + 1536;              // 512 floats
    float* b3s = b2s + 512;               // 256 floats

    prep_weights<<<201, 256, 0, stream>>>(W1, b1, W2, b2, W3, b3,
                                          w2A, w3A, w1p, b2s, b3s);
    node_kernel<<<Bn / RB, NTH, 0, stream>>>(y0, tp, W4, b4,
                                             w2A, w3A, w1p, b2s, b3s, out, Bn, T);
}